// Round 7
// baseline (341.887 us; speedup 1.0000x reference)
//
#include <hip/hip_runtime.h>

// out[b, t, h] = sum_{j=0..4} x[b, t+j, h] * attn[b, t+j]
// B=32, H=768, LENGTH=2048, PADDED=2052, fp32 in/out. Memory-bound streaming.
//
// R7: BATCH-SWEEP decomposition (compact advancing window), replacing the
// per-wave blocked-stream design of R0-R6.
// Evidence: full cache-policy matrix flat at 3.4-4.0 TB/s (nt/nt 108.5,
// nt/plain 112, cached/nt 125, cached/plain 118 us), concurrency- and
// ILP-insensitive; yet fill (write-only, grid-stride) = 6.6 TB/s and m13
// copy (mixed 1:1 R/W, grid-stride) = 6.29 TB/s. The difference is the
// pattern: our ~2048 private 200KB streams scatter 1KB bursts over 400 MB
// -> DRAM row/bank thrash. This version sweeps batch-by-batch: step i
// processes batch i across the whole grid; active window <= ~2 batches
// (~25 MB) advancing monotonically, like the copy.
//  - block = 192 threads (3 waves) owns row-pair p for all 32 batches:
//    reads x rows 2p..2p+5 (6 indep loads), writes out rows 2p, 2p+1.
//  - XCD swizzle p = (bid%8)*128 + bid/8 (bijective, 1024%8==0): the 3
//    reader-blocks of any x row are pair-adjacent -> same XCD -> x re-reads
//    (3x logical) hit the 4MB per-XCD L2; HBM reads stay ~1x.
//  - plain loads (need L2 reuse) + plain stores (L2 write-batching, like
//    the 6.6 TB/s fill). attn/addresses fully block-uniform -> SGPR.

#define LEN     2048
#define WIDTH   5
#define PADDED  (LEN + WIDTH - 1)   // 2052
#define BATCH   32
#define HDIM    768
#define H4      (HDIM / 4)          // 192 float4 per row
#define NPAIR   (LEN / 2)           // 1024 row-pairs
#define NXCD    8

typedef float vfloat4 __attribute__((ext_vector_type(4)));

__global__ __launch_bounds__(192) void widthap_kernel(
    const vfloat4* __restrict__ x,
    const float*   __restrict__ attn,
    vfloat4*       __restrict__ out)
{
    // XCD-swizzled pair index: XCD k owns pairs [k*128, (k+1)*128) ->
    // re-reads of shared x rows stay on one XCD's L2.
    const int bid = blockIdx.x;
    const int p   = (bid % NXCD) * (NPAIR / NXCD) + bid / NXCD;  // SGPR
    const int h4  = threadIdx.x;                                  // 0..191
    const int t0  = 2 * p;                                        // first out row

    const vfloat4* xp = x    + (size_t)t0 * H4 + h4;   // batch 0
    const float*   ap = attn + t0;                     // block-uniform -> s_load
    vfloat4*       op = out  + (size_t)t0 * H4 + h4;

    for (int b = 0; b < BATCH; ++b) {
        // 6 block-uniform attn scalars (rows t0..t0+5)
        const float a0 = ap[0], a1 = ap[1], a2 = ap[2],
                    a3 = ap[3], a4 = ap[4], a5 = ap[5];
        // 6 independent cached row loads (natural ILP=6)
        const vfloat4 v0 = xp[0 * (size_t)H4];
        const vfloat4 v1 = xp[1 * (size_t)H4];
        const vfloat4 v2 = xp[2 * (size_t)H4];
        const vfloat4 v3 = xp[3 * (size_t)H4];
        const vfloat4 v4 = xp[4 * (size_t)H4];
        const vfloat4 v5 = xp[5 * (size_t)H4];

        const vfloat4 s0 = v0*a0 + v1*a1 + v2*a2 + v3*a3 + v4*a4;
        const vfloat4 s1 = v1*a1 + v2*a2 + v3*a3 + v4*a4 + v5*a5;

        op[0]          = s0;     // plain stores: L2 write-batching
        op[(size_t)H4] = s1;

        xp += (size_t)PADDED * H4;   // next batch
        ap += PADDED;
        op += (size_t)LEN * H4;
    }
}

extern "C" void kernel_launch(void* const* d_in, const int* in_sizes, int n_in,
                              void* d_out, int out_size, void* d_ws, size_t ws_size,
                              hipStream_t stream) {
    const vfloat4* x    = (const vfloat4*)d_in[0];  // (32,1,2052,768) fp32
    const float*   attn = (const float*)d_in[1];    // (32,2052) fp32
    vfloat4*       out  = (vfloat4*)d_out;          // (32,1,2048,768) fp32

    const int grid  = NPAIR;   // 1024 blocks (4/CU, 12 waves/CU)
    const int block = H4;      // 192 threads = 3 waves, one full row width
    widthap_kernel<<<grid, block, 0, stream>>>(x, attn, out);
}